// Round 2
// baseline (2568.415 us; speedup 1.0000x reference)
//
#include <hip/hip_runtime.h>

// ---- problem constants ----
#define DEPTH   4
#define N_MOLS  2000
#define APM     50
#define N_ATOMS 100001
#define N_BONDS 200001
#define MAX_NB  6
#define AF      133
#define BF      147
#define H       300

// ---- padded layout ----
#define SB    304     // message row stride (300 used + 4 pad; GEMM reads 320-wide, W rows 300..319 are zero)
#define SF    152     // f_bonds/f_atoms fp16 row stride (reads 160-wide, W rows >=147/133 zero)
#define SW    480     // combined weight K rows per col: [W_h(320) ; W_i(160)] / [Wo_amsg(320) ; Wo_fatoms(160)]
#define MB_P  200016  // bonds padded to x16
#define MA_P  100016  // atoms padded to x16

typedef _Float16 f16x8 __attribute__((ext_vector_type(8)));
typedef float    f32x4 __attribute__((ext_vector_type(4)));

// ---------------- cast / prep ----------------

__global__ void cast_fb_kernel(const float* __restrict__ src, _Float16* __restrict__ dst) {
    unsigned i = blockIdx.x * blockDim.x + threadIdx.x;
    if (i >= (unsigned)MB_P * SF) return;
    unsigned m = i / SF, k = i % SF;
    dst[i] = (_Float16)((m < N_BONDS && k < BF) ? src[(size_t)m * BF + k] : 0.f);
}

__global__ void cast_fa_kernel(const float* __restrict__ src, _Float16* __restrict__ dst) {
    unsigned i = blockIdx.x * blockDim.x + threadIdx.x;
    if (i >= (unsigned)MA_P * SF) return;
    unsigned m = i / SF, k = i % SF;
    dst[i] = (_Float16)((m < N_ATOMS && k < AF) ? src[(size_t)m * AF + k] : 0.f);
}

// Wt[col][r], r in [0,480): rows 0..319 from W_h (zero-padded past 300), rows 320..479 from W_i (zero past 147)
__global__ void cast_whi_kernel(const float* __restrict__ Wh, const float* __restrict__ Wi,
                                _Float16* __restrict__ Wt) {
    int i = blockIdx.x * blockDim.x + threadIdx.x;
    if (i >= 320 * SW) return;
    int n = i / SW, r = i % SW;
    float v = 0.f;
    if (n < H) {
        if (r < 320) { if (r < H) v = Wh[r * H + n]; }
        else         { int rr = r - 320; if (rr < BF) v = Wi[rr * H + n]; }
    }
    Wt[i] = (_Float16)v;
}

// W_o rows: 0..132 = f_atoms part, 133..432 = a_message part.
// Our A order: [a_message(320) | f_atoms(160)]
__global__ void cast_wo_kernel(const float* __restrict__ Wo, _Float16* __restrict__ Wt) {
    int i = blockIdx.x * blockDim.x + threadIdx.x;
    if (i >= 320 * SW) return;
    int n = i / SW, r = i % SW;
    float v = 0.f;
    if (n < H) {
        if (r < 320) { if (r < H) v = Wo[(AF + r) * H + n]; }
        else         { int rr = r - 320; if (rr < AF) v = Wo[rr * H + n]; }
    }
    Wt[i] = (_Float16)v;
}

// ---------------- GEMM ----------------
// C/D layout (16x16x32_f16): A lane holds A[m=lane&15][k=quad*8+j]; B lane holds Wt[n=lane&15][k=quad*8+j];
// D: row=quad*4+e, col=lane&15.
// MODE 0: msg0 = relu(fb @ W_i)                                       (5 K-steps, Wt offset 320)
// MODE 1: msgDst = relu( upd(b) @ W_h + fb(b) @ W_i )                 (10 + 5 K-steps)
//         upd(b)[k] = amsg[b2a[b]][k] - w_bonds[b] * msgSrc[b2revb[b]][k]
// MODE 2: ah = relu( [amsg | fa] @ W_o + b_o )                        (10 + 5 K-steps)
template<int MODE>
__global__ __launch_bounds__(256) void gemm_kernel(
    const _Float16* __restrict__ P1,     // MODE0: fb ; MODE1: amsg ; MODE2: amsg
    const _Float16* __restrict__ P2,     // MODE1: msgSrc ; MODE2: fa
    const _Float16* __restrict__ P3,     // MODE1: fb
    const _Float16* __restrict__ Wt,
    const float* __restrict__ bias,
    const int* __restrict__ b2a,
    const int* __restrict__ b2revb,
    const float* __restrict__ w_bonds,
    _Float16* __restrict__ out,
    int mtiles)
{
    const int lane = threadIdx.x & 63;
    const int wave = threadIdx.x >> 6;
    const int r16  = lane & 15;
    const int quad = lane >> 4;
    const int col  = (blockIdx.x * 4 + wave) * 16 + r16;

    constexpr int NK   = (MODE == 0) ? 5 : 15;
    constexpr int WOFF = (MODE == 0) ? 320 : 0;

    f16x8 bfrag[NK];
    {
        const _Float16* wp = Wt + (size_t)col * SW + WOFF + quad * 8;
        #pragma unroll
        for (int ks = 0; ks < NK; ++ks)
            bfrag[ks] = *(const f16x8*)(wp + ks * 32);
    }

    for (int t = blockIdx.y; t < mtiles; t += gridDim.y) {
        const int row = t * 16 + r16;
        f32x4 acc = {0.f, 0.f, 0.f, 0.f};

        if (MODE == 0) {
            const _Float16* ap = P1 + (size_t)row * SF + quad * 8;
            #pragma unroll
            for (int ks = 0; ks < 5; ++ks)
                acc = __builtin_amdgcn_mfma_f32_16x16x32_f16(*(const f16x8*)(ap + ks * 32),
                                                             bfrag[ks], acc, 0, 0, 0);
        } else if (MODE == 1) {
            const int b = (row < N_BONDS) ? row : 0;   // clamp pad rows: index arrays are size N_BONDS
            const int a  = b2a[b];
            const int rb = b2revb[b];
            const _Float16 w = (_Float16)w_bonds[b];
            const f16x8 wv = {w, w, w, w, w, w, w, w};
            const _Float16* apa = P1 + (size_t)a  * SB + quad * 8;
            const _Float16* apm = P2 + (size_t)rb * SB + quad * 8;
            const _Float16* apf = P3 + (size_t)row * SF + quad * 8;
            #pragma unroll
            for (int ks = 0; ks < 10; ++ks) {
                f16x8 x = *(const f16x8*)(apa + ks * 32);
                f16x8 y = *(const f16x8*)(apm + ks * 32);
                f16x8 u = x - wv * y;
                acc = __builtin_amdgcn_mfma_f32_16x16x32_f16(u, bfrag[ks], acc, 0, 0, 0);
            }
            #pragma unroll
            for (int ks = 0; ks < 5; ++ks)
                acc = __builtin_amdgcn_mfma_f32_16x16x32_f16(*(const f16x8*)(apf + ks * 32),
                                                             bfrag[10 + ks], acc, 0, 0, 0);
        } else {
            const _Float16* apa = P1 + (size_t)row * SB + quad * 8;
            const _Float16* apf = P2 + (size_t)row * SF + quad * 8;
            #pragma unroll
            for (int ks = 0; ks < 10; ++ks)
                acc = __builtin_amdgcn_mfma_f32_16x16x32_f16(*(const f16x8*)(apa + ks * 32),
                                                             bfrag[ks], acc, 0, 0, 0);
            #pragma unroll
            for (int ks = 0; ks < 5; ++ks)
                acc = __builtin_amdgcn_mfma_f32_16x16x32_f16(*(const f16x8*)(apf + ks * 32),
                                                             bfrag[10 + ks], acc, 0, 0, 0);
        }

        if (col < SB) {   // cols 300..303 get exact 0 (zero W cols) keeping pad clean
            const float bv = (MODE == 2 && col < H) ? bias[col] : 0.f;
            const size_t base = (size_t)(t * 16 + quad * 4) * SB + col;
            #pragma unroll
            for (int e = 0; e < 4; ++e) {
                float v = acc[e] + bv;
                out[base + (size_t)e * SB] = (_Float16)(v > 0.f ? v : 0.f);
            }
        }
    }
}

// ---------------- aggregate: amsg[a][:] = sum_k w_bonds[a2b[a][k]] * msg[a2b[a][k]][:] ----------------
// one wave per atom; lanes 0..37 each own 8 contiguous cols (38*8 = 304)
__global__ __launch_bounds__(256) void aggregate_kernel(
    const _Float16* __restrict__ msg,
    const int* __restrict__ a2b,
    const float* __restrict__ w_bonds,
    _Float16* __restrict__ amsg)
{
    const int lane = threadIdx.x & 63;
    const int a = blockIdx.x * 4 + (threadIdx.x >> 6);
    if (a >= N_ATOMS || lane >= 38) return;
    const int h0 = lane * 8;
    float acc[8] = {0, 0, 0, 0, 0, 0, 0, 0};
    #pragma unroll
    for (int k = 0; k < MAX_NB; ++k) {
        const int b = a2b[a * MAX_NB + k];
        const float w = w_bonds[b];
        f16x8 m = *(const f16x8*)(msg + (size_t)b * SB + h0);
        #pragma unroll
        for (int j = 0; j < 8; ++j) acc[j] += w * (float)m[j];
    }
    f16x8 o;
    #pragma unroll
    for (int j = 0; j < 8; ++j) o[j] = (_Float16)acc[j];
    *(f16x8*)(amsg + (size_t)a * SB + h0) = o;
}

// ---------------- readout ----------------
__global__ __launch_bounds__(256) void readout_kernel(
    const _Float16* __restrict__ ah,
    const float* __restrict__ w_atoms,
    const float* __restrict__ dop,
    float* __restrict__ out)
{
    const int lane = threadIdx.x & 63;
    const int m = blockIdx.x * 4 + (threadIdx.x >> 6);
    if (m >= N_MOLS || lane >= 38) return;
    const int h0 = lane * 8;
    const int a0 = 1 + m * APM;
    float acc[8] = {0, 0, 0, 0, 0, 0, 0, 0};
    float wsum = 0.f;
    for (int i = 0; i < APM; ++i) {
        const float w = w_atoms[a0 + i];
        wsum += w;
        f16x8 v = *(const f16x8*)(ah + (size_t)(a0 + i) * SB + h0);
        #pragma unroll
        for (int j = 0; j < 8; ++j) acc[j] += w * (float)v[j];
    }
    const float s = dop[m] / wsum;
    #pragma unroll
    for (int j = 0; j < 8; ++j) {
        const int h = h0 + j;
        if (h < H) out[(size_t)m * H + h] = s * acc[j];
    }
}

// ---------------- launch ----------------
extern "C" void kernel_launch(void* const* d_in, const int* in_sizes, int n_in,
                              void* d_out, int out_size, void* d_ws, size_t ws_size,
                              hipStream_t stream) {
    const float* f_atoms = (const float*)d_in[0];
    const float* f_bonds = (const float*)d_in[1];
    const float* w_atoms = (const float*)d_in[2];
    const float* w_bonds = (const float*)d_in[3];
    const float* dop     = (const float*)d_in[4];
    const float* W_i     = (const float*)d_in[5];
    const float* W_h     = (const float*)d_in[6];
    const float* W_o     = (const float*)d_in[7];
    const float* b_o     = (const float*)d_in[8];
    const int* a2b    = (const int*)d_in[9];
    const int* b2a    = (const int*)d_in[10];
    const int* b2revb = (const int*)d_in[11];
    float* out = (float*)d_out;

    char* p = (char*)d_ws;
    auto alloc = [&](size_t elems) {
        _Float16* q = (_Float16*)p;
        p += ((elems * sizeof(_Float16) + 64 /*tail pad for 320-wide overreads*/ + 255) / 256) * 256;
        return q;
    };
    _Float16* fb16 = alloc((size_t)MB_P * SF);   // 60.8 MB
    _Float16* fa16 = alloc((size_t)MA_P * SF);   // 30.4 MB
    _Float16* msgA = alloc((size_t)MB_P * SB);   // 121.6 MB
    _Float16* msgB = alloc((size_t)MB_P * SB);   // 121.6 MB
    _Float16* amsg = alloc((size_t)MA_P * SB);   // 60.8 MB
    _Float16* Wthi = alloc((size_t)320 * SW);    // 0.3 MB
    _Float16* Wto  = alloc((size_t)320 * SW);    // 0.3 MB  -> total ~396 MB
    _Float16* ah   = msgA;                       // output GEMM reuses dead msgA

    // workspace guard: fail cleanly (absmax = |ref|max) instead of faulting
    if ((size_t)(p - (char*)d_ws) > ws_size) {
        hipMemsetAsync(d_out, 0, (size_t)out_size * sizeof(float), stream);
        return;
    }

    {
        unsigned n1 = (unsigned)MB_P * SF;
        cast_fb_kernel<<<(n1 + 255) / 256, 256, 0, stream>>>(f_bonds, fb16);
        unsigned n2 = (unsigned)MA_P * SF;
        cast_fa_kernel<<<(n2 + 255) / 256, 256, 0, stream>>>(f_atoms, fa16);
        cast_whi_kernel<<<(320 * SW + 255) / 256, 256, 0, stream>>>(W_h, W_i, Wthi);
        cast_wo_kernel<<<(320 * SW + 255) / 256, 256, 0, stream>>>(W_o, Wto);
    }

    const dim3 ggrid(5, 2048);            // 5 blocks x 4 waves x 16 cols = 320 cols
    const int mtilesB = MB_P / 16;        // 12501
    const int mtilesA = MA_P / 16;        // 6251
    const int aggGrid = (N_ATOMS + 3) / 4;

    // msgA = relu(f_bonds @ W_i)
    gemm_kernel<0><<<ggrid, 256, 0, stream>>>(fb16, nullptr, nullptr, Wthi, nullptr,
                                              nullptr, nullptr, nullptr, msgA, mtilesB);
    _Float16* src = msgA;
    _Float16* dst = msgB;
    for (int d = 0; d < DEPTH - 1; ++d) {
        aggregate_kernel<<<aggGrid, 256, 0, stream>>>(src, a2b, w_bonds, amsg);
        gemm_kernel<1><<<ggrid, 256, 0, stream>>>(amsg, src, fb16, Wthi, nullptr,
                                                  b2a, b2revb, w_bonds, dst, mtilesB);
        _Float16* t = src; src = dst; dst = t;
    }
    // src == msgB after 3 layers
    aggregate_kernel<<<aggGrid, 256, 0, stream>>>(src, a2b, w_bonds, amsg);
    gemm_kernel<2><<<ggrid, 256, 0, stream>>>(amsg, fa16, nullptr, Wto, b_o,
                                              nullptr, nullptr, nullptr, ah, mtilesA);
    readout_kernel<<<(N_MOLS + 3) / 4, 256, 0, stream>>>(ah, w_atoms, dop, out);
}

// Round 3
// 2567.695 us; speedup vs baseline: 1.0003x; 1.0003x over previous
//
#include <hip/hip_runtime.h>

// ---- problem constants ----
#define DEPTH   4
#define N_MOLS  2000
#define APM     50
#define N_ATOMS 100001
#define N_BONDS 200001
#define MAX_NB  6
#define AF      133
#define BF      147
#define H       300

// ---- padded layout ----
#define SB    304     // message row stride (300 used + 4 pad; GEMM reads 320-wide, W rows 300..319 are zero)
#define SF    152     // f_bonds/f_atoms fp16 row stride (reads 160-wide, W rows >=147/133 zero)
#define SW    480     // combined weight K rows per col: [W_h(320) ; W_i(160)] / [Wo_amsg(320) ; Wo_fatoms(160)]
#define MB_P  200016  // bonds padded to x16
#define MA_P  100016  // atoms padded to x16

typedef _Float16 f16x8 __attribute__((ext_vector_type(8)));
typedef float    f32x4 __attribute__((ext_vector_type(4)));

// ---------------- cast / prep ----------------

__global__ void cast_fb_kernel(const float* __restrict__ src, _Float16* __restrict__ dst) {
    unsigned i = blockIdx.x * blockDim.x + threadIdx.x;
    if (i >= (unsigned)MB_P * SF) return;
    unsigned m = i / SF, k = i % SF;
    dst[i] = (_Float16)((m < N_BONDS && k < BF) ? src[(size_t)m * BF + k] : 0.f);
}

__global__ void cast_fa_kernel(const float* __restrict__ src, _Float16* __restrict__ dst) {
    unsigned i = blockIdx.x * blockDim.x + threadIdx.x;
    if (i >= (unsigned)MA_P * SF) return;
    unsigned m = i / SF, k = i % SF;
    dst[i] = (_Float16)((m < N_ATOMS && k < AF) ? src[(size_t)m * AF + k] : 0.f);
}

// Wt[col][r], r in [0,480): rows 0..319 from W_h (zero-padded past 300), rows 320..479 from W_i (zero past 147)
__global__ void cast_whi_kernel(const float* __restrict__ Wh, const float* __restrict__ Wi,
                                _Float16* __restrict__ Wt) {
    int i = blockIdx.x * blockDim.x + threadIdx.x;
    if (i >= 320 * SW) return;
    int n = i / SW, r = i % SW;
    float v = 0.f;
    if (n < H) {
        if (r < 320) { if (r < H) v = Wh[r * H + n]; }
        else         { int rr = r - 320; if (rr < BF) v = Wi[rr * H + n]; }
    }
    Wt[i] = (_Float16)v;
}

// W_o rows: 0..132 = f_atoms part, 133..432 = a_message part.
// Our A order: [a_message(320) | f_atoms(160)]
__global__ void cast_wo_kernel(const float* __restrict__ Wo, _Float16* __restrict__ Wt) {
    int i = blockIdx.x * blockDim.x + threadIdx.x;
    if (i >= 320 * SW) return;
    int n = i / SW, r = i % SW;
    float v = 0.f;
    if (n < H) {
        if (r < 320) { if (r < H) v = Wo[(AF + r) * H + n]; }
        else         { int rr = r - 320; if (rr < AF) v = Wo[rr * H + n]; }
    }
    Wt[i] = (_Float16)v;
}

// ---------------- GEMM ----------------
// C/D layout (16x16x32_f16): A lane holds A[m=lane&15][k=quad*8+j]; B lane holds Wt[n=lane&15][k=quad*8+j];
// D: row=quad*4+e, col=lane&15.
// MODE 0: msg0 = relu(fb @ W_i)                                       (5 K-steps, Wt offset 320)
// MODE 1: msgDst = relu( upd(b) @ W_h + fb(b) @ W_i )                 (10 + 5 K-steps)
//         upd(b)[k] = amsg[b2a[b]][k] - w_bonds[b] * msgSrc[b2revb[b]][k]
// MODE 2: ah = relu( [amsg | fa] @ W_o + b_o )                        (10 + 5 K-steps)
//
// R3: all A-side fragments are prefetched into register arrays BEFORE the MFMA
// chain — R2's 48-VGPR version serialized ~15 gather loads per tile at L3/HBM
// latency (MfmaUtil 4%, HBM 22%). Registers are the cheapest fix.
template<int MODE>
__global__ __launch_bounds__(256) void gemm_kernel(
    const _Float16* __restrict__ P1,     // MODE0: fb ; MODE1: amsg ; MODE2: amsg
    const _Float16* __restrict__ P2,     // MODE1: msgSrc ; MODE2: fa
    const _Float16* __restrict__ P3,     // MODE1: fb
    const _Float16* __restrict__ Wt,
    const float* __restrict__ bias,
    const int* __restrict__ b2a,
    const int* __restrict__ b2revb,
    const float* __restrict__ w_bonds,
    _Float16* __restrict__ out,
    int mtiles)
{
    const int lane = threadIdx.x & 63;
    const int wave = threadIdx.x >> 6;
    const int r16  = lane & 15;
    const int quad = lane >> 4;
    const int col  = (blockIdx.x * 4 + wave) * 16 + r16;

    constexpr int NK   = (MODE == 0) ? 5 : 15;
    constexpr int WOFF = (MODE == 0) ? 320 : 0;

    f16x8 bfrag[NK];
    {
        const _Float16* wp = Wt + (size_t)col * SW + WOFF + quad * 8;
        #pragma unroll
        for (int ks = 0; ks < NK; ++ks)
            bfrag[ks] = *(const f16x8*)(wp + ks * 32);
    }

    for (int t = blockIdx.y; t < mtiles; t += gridDim.y) {
        const int row = t * 16 + r16;
        f32x4 acc = {0.f, 0.f, 0.f, 0.f};

        if (MODE == 0) {
            const _Float16* ap = P1 + (size_t)row * SF + quad * 8;
            f16x8 ff[5];
            #pragma unroll
            for (int ks = 0; ks < 5; ++ks) ff[ks] = *(const f16x8*)(ap + ks * 32);
            #pragma unroll
            for (int ks = 0; ks < 5; ++ks)
                acc = __builtin_amdgcn_mfma_f32_16x16x32_f16(ff[ks], bfrag[ks], acc, 0, 0, 0);
        } else if (MODE == 1) {
            const int b = (row < N_BONDS) ? row : 0;   // clamp pad rows
            const int a  = b2a[b];
            const int rb = b2revb[b];
            const _Float16 w = (_Float16)w_bonds[b];
            const _Float16* apa = P1 + (size_t)a  * SB + quad * 8;
            const _Float16* apm = P2 + (size_t)rb * SB + quad * 8;
            const _Float16* apf = P3 + (size_t)row * SF + quad * 8;
            f16x8 xa[10], ym[10], ff[5];
            #pragma unroll
            for (int ks = 0; ks < 10; ++ks) xa[ks] = *(const f16x8*)(apa + ks * 32);
            #pragma unroll
            for (int ks = 0; ks < 10; ++ks) ym[ks] = *(const f16x8*)(apm + ks * 32);
            #pragma unroll
            for (int ks = 0; ks < 5; ++ks)  ff[ks] = *(const f16x8*)(apf + ks * 32);
            const f16x8 wv = {w, w, w, w, w, w, w, w};
            #pragma unroll
            for (int ks = 0; ks < 10; ++ks) {
                f16x8 u = xa[ks] - wv * ym[ks];
                acc = __builtin_amdgcn_mfma_f32_16x16x32_f16(u, bfrag[ks], acc, 0, 0, 0);
            }
            #pragma unroll
            for (int ks = 0; ks < 5; ++ks)
                acc = __builtin_amdgcn_mfma_f32_16x16x32_f16(ff[ks], bfrag[10 + ks], acc, 0, 0, 0);
        } else {
            const _Float16* apa = P1 + (size_t)row * SB + quad * 8;
            const _Float16* apf = P2 + (size_t)row * SF + quad * 8;
            f16x8 xa[10], ff[5];
            #pragma unroll
            for (int ks = 0; ks < 10; ++ks) xa[ks] = *(const f16x8*)(apa + ks * 32);
            #pragma unroll
            for (int ks = 0; ks < 5; ++ks)  ff[ks] = *(const f16x8*)(apf + ks * 32);
            #pragma unroll
            for (int ks = 0; ks < 10; ++ks)
                acc = __builtin_amdgcn_mfma_f32_16x16x32_f16(xa[ks], bfrag[ks], acc, 0, 0, 0);
            #pragma unroll
            for (int ks = 0; ks < 5; ++ks)
                acc = __builtin_amdgcn_mfma_f32_16x16x32_f16(ff[ks], bfrag[10 + ks], acc, 0, 0, 0);
        }

        if (col < SB) {   // cols 300..303 get exact 0 (zero W cols) keeping pad clean
            const float bv = (MODE == 2 && col < H) ? bias[col] : 0.f;
            const size_t base = (size_t)(t * 16 + quad * 4) * SB + col;
            #pragma unroll
            for (int e = 0; e < 4; ++e) {
                float v = acc[e] + bv;
                out[base + (size_t)e * SB] = (_Float16)(v > 0.f ? v : 0.f);
            }
        }
    }
}

// ---------------- aggregate: amsg[a][:] = sum_k w_bonds[a2b[a][k]] * msg[a2b[a][k]][:] ----------------
// one wave per atom; lanes 0..37 each own 8 contiguous cols (38*8 = 304)
// R3: all 6 gathered rows issued before the accumulate (MLP).
__global__ __launch_bounds__(256) void aggregate_kernel(
    const _Float16* __restrict__ msg,
    const int* __restrict__ a2b,
    const float* __restrict__ w_bonds,
    _Float16* __restrict__ amsg)
{
    const int lane = threadIdx.x & 63;
    const int a = blockIdx.x * 4 + (threadIdx.x >> 6);
    if (a >= N_ATOMS || lane >= 38) return;
    const int h0 = lane * 8;
    int   bidx[MAX_NB];
    float wv[MAX_NB];
    f16x8 rows[MAX_NB];
    #pragma unroll
    for (int k = 0; k < MAX_NB; ++k) bidx[k] = a2b[a * MAX_NB + k];
    #pragma unroll
    for (int k = 0; k < MAX_NB; ++k) wv[k] = w_bonds[bidx[k]];
    #pragma unroll
    for (int k = 0; k < MAX_NB; ++k)
        rows[k] = *(const f16x8*)(msg + (size_t)bidx[k] * SB + h0);
    float acc[8] = {0, 0, 0, 0, 0, 0, 0, 0};
    #pragma unroll
    for (int k = 0; k < MAX_NB; ++k) {
        #pragma unroll
        for (int j = 0; j < 8; ++j) acc[j] += wv[k] * (float)rows[k][j];
    }
    f16x8 o;
    #pragma unroll
    for (int j = 0; j < 8; ++j) o[j] = (_Float16)acc[j];
    *(f16x8*)(amsg + (size_t)a * SB + h0) = o;
}

// ---------------- readout ----------------
__global__ __launch_bounds__(256) void readout_kernel(
    const _Float16* __restrict__ ah,
    const float* __restrict__ w_atoms,
    const float* __restrict__ dop,
    float* __restrict__ out)
{
    const int lane = threadIdx.x & 63;
    const int m = blockIdx.x * 4 + (threadIdx.x >> 6);
    if (m >= N_MOLS || lane >= 38) return;
    const int h0 = lane * 8;
    const int a0 = 1 + m * APM;
    float acc[8] = {0, 0, 0, 0, 0, 0, 0, 0};
    float wsum = 0.f;
    for (int i = 0; i < APM; ++i) {
        const float w = w_atoms[a0 + i];
        wsum += w;
        f16x8 v = *(const f16x8*)(ah + (size_t)(a0 + i) * SB + h0);
        #pragma unroll
        for (int j = 0; j < 8; ++j) acc[j] += w * (float)v[j];
    }
    const float s = dop[m] / wsum;
    #pragma unroll
    for (int j = 0; j < 8; ++j) {
        const int h = h0 + j;
        if (h < H) out[(size_t)m * H + h] = s * acc[j];
    }
}

// ---------------- launch ----------------
extern "C" void kernel_launch(void* const* d_in, const int* in_sizes, int n_in,
                              void* d_out, int out_size, void* d_ws, size_t ws_size,
                              hipStream_t stream) {
    const float* f_atoms = (const float*)d_in[0];
    const float* f_bonds = (const float*)d_in[1];
    const float* w_atoms = (const float*)d_in[2];
    const float* w_bonds = (const float*)d_in[3];
    const float* dop     = (const float*)d_in[4];
    const float* W_i     = (const float*)d_in[5];
    const float* W_h     = (const float*)d_in[6];
    const float* W_o     = (const float*)d_in[7];
    const float* b_o     = (const float*)d_in[8];
    const int* a2b    = (const int*)d_in[9];
    const int* b2a    = (const int*)d_in[10];
    const int* b2revb = (const int*)d_in[11];
    float* out = (float*)d_out;

    char* p = (char*)d_ws;
    auto alloc = [&](size_t elems) {
        _Float16* q = (_Float16*)p;
        p += ((elems * sizeof(_Float16) + 64 /*tail pad for 320-wide overreads*/ + 255) / 256) * 256;
        return q;
    };
    _Float16* fb16 = alloc((size_t)MB_P * SF);   // 60.8 MB
    _Float16* fa16 = alloc((size_t)MA_P * SF);   // 30.4 MB
    _Float16* msgA = alloc((size_t)MB_P * SB);   // 121.6 MB
    _Float16* msgB = alloc((size_t)MB_P * SB);   // 121.6 MB
    _Float16* amsg = alloc((size_t)MA_P * SB);   // 60.8 MB
    _Float16* Wthi = alloc((size_t)320 * SW);    // 0.3 MB
    _Float16* Wto  = alloc((size_t)320 * SW);    // 0.3 MB  -> total ~396 MB
    _Float16* ah   = msgA;                       // output GEMM reuses dead msgA

    // workspace guard: fail cleanly (absmax = |ref|max) instead of faulting
    if ((size_t)(p - (char*)d_ws) > ws_size) {
        hipMemsetAsync(d_out, 0, (size_t)out_size * sizeof(float), stream);
        return;
    }

    {
        unsigned n1 = (unsigned)MB_P * SF;
        cast_fb_kernel<<<(n1 + 255) / 256, 256, 0, stream>>>(f_bonds, fb16);
        unsigned n2 = (unsigned)MA_P * SF;
        cast_fa_kernel<<<(n2 + 255) / 256, 256, 0, stream>>>(f_atoms, fa16);
        cast_whi_kernel<<<(320 * SW + 255) / 256, 256, 0, stream>>>(W_h, W_i, Wthi);
        cast_wo_kernel<<<(320 * SW + 255) / 256, 256, 0, stream>>>(W_o, Wto);
    }

    const dim3 ggrid(5, 2048);            // 5 blocks x 4 waves x 16 cols = 320 cols
    const int mtilesB = MB_P / 16;        // 12501
    const int mtilesA = MA_P / 16;        // 6251
    const int aggGrid = (N_ATOMS + 3) / 4;

    // msgA = relu(f_bonds @ W_i)
    gemm_kernel<0><<<ggrid, 256, 0, stream>>>(fb16, nullptr, nullptr, Wthi, nullptr,
                                              nullptr, nullptr, nullptr, msgA, mtilesB);
    _Float16* src = msgA;
    _Float16* dst = msgB;
    for (int d = 0; d < DEPTH - 1; ++d) {
        aggregate_kernel<<<aggGrid, 256, 0, stream>>>(src, a2b, w_bonds, amsg);
        gemm_kernel<1><<<ggrid, 256, 0, stream>>>(amsg, src, fb16, Wthi, nullptr,
                                                  b2a, b2revb, w_bonds, dst, mtilesB);
        _Float16* t = src; src = dst; dst = t;
    }
    // src == msgB after 3 layers
    aggregate_kernel<<<aggGrid, 256, 0, stream>>>(src, a2b, w_bonds, amsg);
    gemm_kernel<2><<<ggrid, 256, 0, stream>>>(amsg, fa16, nullptr, Wto, b_o,
                                              nullptr, nullptr, nullptr, ah, mtilesA);
    readout_kernel<<<(N_MOLS + 3) / 4, 256, 0, stream>>>(ah, w_atoms, dop, out);
}

// Round 4
// 1350.943 us; speedup vs baseline: 1.9012x; 1.9007x over previous
//
#include <hip/hip_runtime.h>

// ---- problem constants ----
#define N_MOLS  2000
#define APM     50
#define N_ATOMS 100001
#define N_BONDS 200001
#define MAX_NB  6
#define AF      133
#define BF      147
#define H       300

// ---- padded layout ----
#define SB    304      // hidden-row stride (fp16 / fp8 elements); 38*8
#define SF    152      // feature-row stride (fp16); 19*8
#define MB_P  200064   // bonds padded to x64 (3126 * 64)
#define MA_P  100096   // atoms padded to x64 (1564 * 64)
#define SWH   320      // Wt_h K-rows per col
#define SWI   160      // Wt_i
#define SWO   480      // Wt_o ([amsg 320 | fa 160])

typedef _Float16 f16x8 __attribute__((ext_vector_type(8)));
typedef float    f32x4 __attribute__((ext_vector_type(4)));

// ---------------- fp8 e4m3 helpers (manual: OCP fn, flush-denorm) ----------------
__device__ inline unsigned int f32_to_fp8(float f) {
    union { _Float16 h; unsigned short u; } cv; cv.h = (_Float16)f;
    const unsigned short u = cv.u;
    const int s = (u >> 15) & 1;
    const int e = (u >> 10) & 31;
    const int m = u & 1023;
    int e8 = e - 8;                       // e - 15 + 7
    if (e8 <= 0) return s << 7;           // underflow/denorm -> 0 (|v| < 2^-6)
    int m8 = (m + 64) >> 7;               // round-nearest
    if (m8 == 8) { m8 = 0; e8 += 1; }
    if (e8 > 15 || (e8 == 15 && m8 > 6)) return (s << 7) | 0x7E;  // clamp 448
    return (s << 7) | (e8 << 3) | m8;
}
__device__ inline float fp8_to_f32(unsigned int c) {
    const int s = (c >> 7) & 1, e = (c >> 3) & 15, m = c & 7;
    if (e == 0) return 0.f;
    union { unsigned short u; _Float16 h; } cv;
    cv.u = (unsigned short)((s << 15) | ((e + 8) << 10) | (m << 7));
    return (float)cv.h;
}

// ---------------- cast / prep ----------------
__global__ void cast_fb_kernel(const float* __restrict__ src, _Float16* __restrict__ dst) {
    unsigned i = blockIdx.x * blockDim.x + threadIdx.x;
    if (i >= (unsigned)MB_P * SF) return;
    unsigned m = i / SF, k = i % SF;
    dst[i] = (_Float16)((m < N_BONDS && k < BF) ? src[(size_t)m * BF + k] : 0.f);
}
__global__ void cast_fa_kernel(const float* __restrict__ src, _Float16* __restrict__ dst) {
    unsigned i = blockIdx.x * blockDim.x + threadIdx.x;
    if (i >= (unsigned)MA_P * SF) return;
    unsigned m = i / SF, k = i % SF;
    dst[i] = (_Float16)((m < N_ATOMS && k < AF) ? src[(size_t)m * AF + k] : 0.f);
}
__global__ void cast_wh_kernel(const float* __restrict__ W, _Float16* __restrict__ Wt) {
    int i = blockIdx.x * blockDim.x + threadIdx.x;
    if (i >= 320 * SWH) return;
    int n = i / SWH, k = i % SWH;
    Wt[i] = (_Float16)((n < H && k < H) ? W[k * H + n] : 0.f);
}
__global__ void cast_wi_kernel(const float* __restrict__ W, _Float16* __restrict__ Wt) {
    int i = blockIdx.x * blockDim.x + threadIdx.x;
    if (i >= 320 * SWI) return;
    int n = i / SWI, k = i % SWI;
    Wt[i] = (_Float16)((n < H && k < BF) ? W[k * H + n] : 0.f);
}
// A order for output GEMM: [a_message(320) | f_atoms(160)]; W_o rows 0..132 = f_atoms, 133..432 = a_message
__global__ void cast_wo_kernel(const float* __restrict__ W, _Float16* __restrict__ Wt) {
    int i = blockIdx.x * blockDim.x + threadIdx.x;
    if (i >= 320 * SWO) return;
    int n = i / SWO, r = i % SWO;
    float v = 0.f;
    if (n < H) {
        if (r < 320) { if (r < H) v = W[(AF + r) * H + n]; }
        else         { int rr = r - 320; if (rr < AF) v = W[rr * H + n]; }
    }
    Wt[i] = (_Float16)v;
}

// ---------------- dense one-pass GEMM ----------------
// Block 256 = 4 waves; tile 64 rows x 320 cols; wave = 32 rows x 160 cols.
// B staged per 32-K chunk in LDS ([320 cols][40 fp16], +8 pad kills 64B-stride conflicts).
// Frag layout (16x16x32_f16, verified in R2): A[m=lane&15][k=quad*8+j], B=Wt[n=lane&15][k=...],
// D row=quad*4+e, col=lane&15.
// MODE 0 (I): A1=fb16(SF), K=160 : out8 = fp8(acc) [inp], out16 = relu(acc) [msg0]
// MODE 1 (H): A1=msg(SB),  K=320 : out16 = acc (linear) [hb]
// MODE 2 (O): A1=amsg(SB) K0..319, A2=fa16(SF) K320..479 : out16 = relu(acc + bias)
template<int NCHUNK, int MODE>
__global__ __launch_bounds__(256, 3) void dgemm_kernel(
    const _Float16* __restrict__ A1, const _Float16* __restrict__ A2,
    const _Float16* __restrict__ Wt, const float* __restrict__ bias,
    _Float16* __restrict__ out16, unsigned char* __restrict__ out8)
{
    __shared__ _Float16 Bs[320 * 40];
    const int tid  = threadIdx.x;
    const int lane = tid & 63, wave = tid >> 6;
    const int r16  = lane & 15, quad = lane >> 4;
    const int rh   = wave >> 1, ch = wave & 1;
    const int row0 = blockIdx.x * 64 + rh * 32 + r16;
    const int colbase = ch * 160;
    constexpr int SW = (MODE == 0) ? SWI : (MODE == 1 ? SWH : SWO);

    f32x4 acc[2][10];
    #pragma unroll
    for (int s = 0; s < 2; ++s)
        #pragma unroll
        for (int ct = 0; ct < 10; ++ct) acc[s][ct] = f32x4{0.f, 0.f, 0.f, 0.f};

    #pragma unroll 1
    for (int kc = 0; kc < NCHUNK; ++kc) {
        __syncthreads();                       // protect previous chunk's LDS reads
        for (int n = tid; n < 320; n += 256) {
            const _Float16* src = Wt + (size_t)n * SW + kc * 32;
            f16x8 t0 = *(const f16x8*)(src + 0);
            f16x8 t1 = *(const f16x8*)(src + 8);
            f16x8 t2 = *(const f16x8*)(src + 16);
            f16x8 t3 = *(const f16x8*)(src + 24);
            *(f16x8*)(&Bs[n * 40 + 0])  = t0;
            *(f16x8*)(&Bs[n * 40 + 8])  = t1;
            *(f16x8*)(&Bs[n * 40 + 16]) = t2;
            *(f16x8*)(&Bs[n * 40 + 24]) = t3;
        }
        __syncthreads();

        const _Float16* ap; int kl, sa;
        if (MODE == 2 && kc >= 10) { ap = A2; kl = kc - 10; sa = SF; }
        else                       { ap = A1; kl = kc; sa = (MODE == 0 ? SF : SB); }
        const f16x8 a0 = *(const f16x8*)(ap + (size_t)row0 * sa + kl * 32 + quad * 8);
        const f16x8 a1 = *(const f16x8*)(ap + (size_t)(row0 + 16) * sa + kl * 32 + quad * 8);
        #pragma unroll
        for (int ct = 0; ct < 10; ++ct) {
            const f16x8 b = *(const f16x8*)(&Bs[(colbase + ct * 16 + r16) * 40 + quad * 8]);
            acc[0][ct] = __builtin_amdgcn_mfma_f32_16x16x32_f16(a0, b, acc[0][ct], 0, 0, 0);
            acc[1][ct] = __builtin_amdgcn_mfma_f32_16x16x32_f16(a1, b, acc[1][ct], 0, 0, 0);
        }
    }

    const int rowb = blockIdx.x * 64 + rh * 32 + quad * 4;
    #pragma unroll
    for (int ct = 0; ct < 10; ++ct) {
        const int col = colbase + ct * 16 + r16;
        if (col >= SB) continue;               // cols 304..319 dropped; 300..303 exact 0
        const float bv = (MODE == 2 && col < H) ? bias[col] : 0.f;
        #pragma unroll
        for (int s = 0; s < 2; ++s) {
            #pragma unroll
            for (int e = 0; e < 4; ++e) {
                const int row = rowb + s * 16 + e;
                const float v = acc[s][ct][e] + bv;
                if (MODE == 0) {
                    out8 [(size_t)row * SB + col] = (unsigned char)f32_to_fp8(v);
                    out16[(size_t)row * SB + col] = (_Float16)(v > 0.f ? v : 0.f);
                } else if (MODE == 1) {
                    out16[(size_t)row * SB + col] = (_Float16)v;
                } else {
                    out16[(size_t)row * SB + col] = (_Float16)(v > 0.f ? v : 0.f);
                }
            }
        }
    }
}

// ---------------- aggregate: dst[a][:] = sum_k w_bonds[a2b[a][k]] * src[a2b[a][k]][:] ----------------
__global__ __launch_bounds__(256, 8) void aggregate_kernel(
    const _Float16* __restrict__ src,
    const int* __restrict__ a2b,
    const float* __restrict__ w_bonds,
    _Float16* __restrict__ dst)
{
    const int lane = threadIdx.x & 63;
    const int a = blockIdx.x * 4 + (threadIdx.x >> 6);
    if (a >= N_ATOMS || lane >= 38) return;
    const int h0 = lane * 8;
    float acc[8] = {0, 0, 0, 0, 0, 0, 0, 0};
    #pragma unroll
    for (int k = 0; k < MAX_NB; ++k) {
        const int b = a2b[a * MAX_NB + k];
        const float w = w_bonds[b];
        const f16x8 m = *(const f16x8*)(src + (size_t)b * SB + h0);
        #pragma unroll
        for (int j = 0; j < 8; ++j) acc[j] += w * (float)m[j];
    }
    f16x8 o;
    #pragma unroll
    for (int j = 0; j < 8; ++j) o[j] = (_Float16)acc[j];
    *(f16x8*)(dst + (size_t)a * SB + h0) = o;
}

// ---------------- bond update: msg[b] = relu(inp[b] + hm[b2a[b]] - w_b * hb[b2revb[b]]) ----------------
__global__ __launch_bounds__(256, 8) void update_kernel(
    const unsigned char* __restrict__ inp8,
    const _Float16* __restrict__ hm,
    const _Float16* __restrict__ hb,
    const int* __restrict__ b2a,
    const int* __restrict__ b2revb,
    const float* __restrict__ w_bonds,
    _Float16* __restrict__ msg)
{
    const int lane = threadIdx.x & 63;
    const int b = blockIdx.x * 4 + (threadIdx.x >> 6);
    if (b >= MB_P || lane >= 38) return;
    const bool real = b < N_BONDS;
    const int bc = real ? b : 0;
    const int a  = b2a[bc];
    const int rb = b2revb[bc];
    const float w = w_bonds[bc];
    const int h0 = lane * 8;
    const uint2 i8  = *(const uint2*)(inp8 + (size_t)b * SB + h0);
    const f16x8 hmv = *(const f16x8*)(hm + (size_t)a  * SB + h0);
    const f16x8 hbv = *(const f16x8*)(hb + (size_t)rb * SB + h0);
    f16x8 o;
    #pragma unroll
    for (int j = 0; j < 8; ++j) {
        const unsigned int c = ((j < 4 ? i8.x : i8.y) >> (8 * (j & 3))) & 255u;
        const float v = fp8_to_f32(c) + (float)hmv[j] - w * (float)hbv[j];
        o[j] = (_Float16)((real && v > 0.f) ? v : 0.f);
    }
    *(f16x8*)(msg + (size_t)b * SB + h0) = o;
}

// ---------------- readout ----------------
__global__ __launch_bounds__(256, 8) void readout_kernel(
    const _Float16* __restrict__ ah,
    const float* __restrict__ w_atoms,
    const float* __restrict__ dop,
    float* __restrict__ out)
{
    const int lane = threadIdx.x & 63;
    const int m = blockIdx.x * 4 + (threadIdx.x >> 6);
    if (m >= N_MOLS || lane >= 38) return;
    const int h0 = lane * 8;
    const int a0 = 1 + m * APM;
    float acc[8] = {0, 0, 0, 0, 0, 0, 0, 0};
    float wsum = 0.f;
    for (int i = 0; i < APM; ++i) {
        const float w = w_atoms[a0 + i];
        wsum += w;
        const f16x8 v = *(const f16x8*)(ah + (size_t)(a0 + i) * SB + h0);
        #pragma unroll
        for (int j = 0; j < 8; ++j) acc[j] += w * (float)v[j];
    }
    const float s = dop[m] / wsum;
    #pragma unroll
    for (int j = 0; j < 8; ++j) {
        const int h = h0 + j;
        if (h < H) out[(size_t)m * H + h] = s * acc[j];
    }
}

// ---------------- launch ----------------
extern "C" void kernel_launch(void* const* d_in, const int* in_sizes, int n_in,
                              void* d_out, int out_size, void* d_ws, size_t ws_size,
                              hipStream_t stream) {
    const float* f_atoms = (const float*)d_in[0];
    const float* f_bonds = (const float*)d_in[1];
    const float* w_atoms = (const float*)d_in[2];
    const float* w_bonds = (const float*)d_in[3];
    const float* dop     = (const float*)d_in[4];
    const float* W_i     = (const float*)d_in[5];
    const float* W_h     = (const float*)d_in[6];
    const float* W_o     = (const float*)d_in[7];
    const float* b_o     = (const float*)d_in[8];
    const int* a2b    = (const int*)d_in[9];
    const int* b2a    = (const int*)d_in[10];
    const int* b2revb = (const int*)d_in[11];
    float* out = (float*)d_out;

    char* p = (char*)d_ws;
    auto alloc = [&](size_t bytes) {
        char* q = p;
        p += ((bytes + 64 /*tail pad for K-overreads*/ + 255) / 256) * 256;
        return q;
    };
    unsigned char* inp8 = (unsigned char*)alloc((size_t)MB_P * SB);          // 60.8 MB
    _Float16* msg  = (_Float16*)alloc((size_t)MB_P * SB * 2);                // 121.6 MB
    _Float16* hb   = (_Float16*)alloc((size_t)MB_P * SB * 2);                // 121.6 MB
    _Float16* hm   = (_Float16*)alloc((size_t)MA_P * SB * 2);                // 60.9 MB
    _Float16* Wth  = (_Float16*)alloc((size_t)320 * SWH * 2);
    _Float16* Wti  = (_Float16*)alloc((size_t)320 * SWI * 2);
    _Float16* Wto  = (_Float16*)alloc((size_t)320 * SWO * 2);                // total ~366 MB
    _Float16* fb16 = hb;                    // fb16 (60.8 MB) lives in hb until first layer GEMM
    _Float16* fa16 = (_Float16*)inp8;       // fa16 (30.4 MB) lives in inp8 after last update
    _Float16* ah   = hb;                    // output-GEMM result reuses dead hb

    if ((size_t)(p - (char*)d_ws) > ws_size) {   // clean failure instead of fault
        hipMemsetAsync(d_out, 0, (size_t)out_size * sizeof(float), stream);
        return;
    }

    // casts
    {
        unsigned n1 = (unsigned)MB_P * SF;
        cast_fb_kernel<<<(n1 + 255) / 256, 256, 0, stream>>>(f_bonds, fb16);
        cast_wh_kernel<<<(320 * SWH + 255) / 256, 256, 0, stream>>>(W_h, Wth);
        cast_wi_kernel<<<(320 * SWI + 255) / 256, 256, 0, stream>>>(W_i, Wti);
        cast_wo_kernel<<<(320 * SWO + 255) / 256, 256, 0, stream>>>(W_o, Wto);
    }

    const int gB = MB_P / 64;             // 3126
    const int gA = MA_P / 64;             // 1564
    const int aggGrid = (N_ATOMS + 3) / 4;
    const int updGrid = MB_P / 4;

    // inp = fb @ W_i (fp8), msg0 = relu(inp)
    dgemm_kernel<5, 0><<<gB, 256, 0, stream>>>(fb16, nullptr, Wti, nullptr, msg, inp8);
    for (int d = 0; d < 3; ++d) {
        // hb = msg @ W_h  (dense, linear)
        dgemm_kernel<10, 1><<<gB, 256, 0, stream>>>(msg, nullptr, Wth, nullptr, hb, nullptr);
        // hm[a] = sum w * hb[a2b]
        aggregate_kernel<<<aggGrid, 256, 0, stream>>>(hb, a2b, w_bonds, hm);
        // msg = relu(inp + hm[b2a] - w * hb[b2revb])   (in place)
        update_kernel<<<updGrid, 256, 0, stream>>>(inp8, hm, hb, b2a, b2revb, w_bonds, msg);
    }
    // final atom aggregation from msg
    aggregate_kernel<<<aggGrid, 256, 0, stream>>>(msg, a2b, w_bonds, hm);
    // fa cast into (dead) inp8 region
    {
        unsigned n2 = (unsigned)MA_P * SF;
        cast_fa_kernel<<<(n2 + 255) / 256, 256, 0, stream>>>(f_atoms, fa16);
    }
    // ah = relu([hm | fa] @ W_o + b_o)
    dgemm_kernel<15, 2><<<gA, 256, 0, stream>>>(hm, fa16, Wto, b_o, ah, nullptr);
    readout_kernel<<<(N_MOLS + 3) / 4, 256, 0, stream>>>(ah, w_atoms, dop, out);
}